// Round 1
// 348.291 us; speedup vs baseline: 1.0025x; 1.0025x over previous
//
#include <hip/hip_runtime.h>

// CTC greedy decoder: argmax over V, then per-row unique_consecutive + blank-drop + compact.
// B=64, T=2048, V=512 (fp32 probs, int32 lengths, int32 outputs).
//
// R1 change: NEVER touch d_ws. tokens scratch aliases d_out (ctc_compact is
// alias-safe by construction: all global reads complete before the first
// __syncthreads, each block touches only its own row). The harness's 1-GiB
// workspace poison fill (~161 us, seen as fillBufferAligned in rocprof) was
// serialized with argmax_rows via a WAW dependency on d_ws; removing all ws
// use takes it off our critical path if the poison is conditional/overlappable.

#define VDIM 512
#define TDIM 2048

// One wave (64 lanes) per (b,t) row of 512 floats.
// Lane loads 2 x float4 (coalesced 16B/lane), local argmax (first-occurrence),
// butterfly reduce with (val desc, idx asc) tie-break.
__global__ __launch_bounds__(256) void argmax_rows(const float* __restrict__ probs,
                                                   int* __restrict__ tokens,
                                                   int nrows) {
    int gid = blockIdx.x * blockDim.x + threadIdx.x;
    int row = gid >> 6;          // wave id = row id
    int lane = threadIdx.x & 63;
    if (row >= nrows) return;

    const float4* p = (const float4*)(probs + (size_t)row * VDIM);
    float4 a = p[lane];          // elements 4*lane .. 4*lane+3
    float4 b = p[lane + 64];     // elements 256+4*lane .. 256+4*lane+3

    float bv = a.x; int bi = 4 * lane;
    // strictly-greater keeps the earliest index (indices ascend within lane)
    if (a.y > bv) { bv = a.y; bi = 4 * lane + 1; }
    if (a.z > bv) { bv = a.z; bi = 4 * lane + 2; }
    if (a.w > bv) { bv = a.w; bi = 4 * lane + 3; }
    if (b.x > bv) { bv = b.x; bi = 256 + 4 * lane; }
    if (b.y > bv) { bv = b.y; bi = 256 + 4 * lane + 1; }
    if (b.z > bv) { bv = b.z; bi = 256 + 4 * lane + 2; }
    if (b.w > bv) { bv = b.w; bi = 256 + 4 * lane + 3; }

    // 64-lane butterfly; ties -> lower index (jnp.argmax first occurrence)
    #pragma unroll
    for (int off = 32; off > 0; off >>= 1) {
        float ov = __shfl_xor(bv, off, 64);
        int   oi = __shfl_xor(bi, off, 64);
        if (ov > bv || (ov == bv && oi < bi)) { bv = ov; bi = oi; }
    }
    if (lane == 0) tokens[row] = bi;
}

// One block (256 threads) per batch row; 8 tokens/thread over T=2048.
// keep = (t < len) && (tok != 0) && (tok != prev); prefix-scan; compact left; zero tail.
// All global READS happen before the first __syncthreads (which drains vmcnt on
// gfx950), so the kernel is safe when `tokens` aliases `out` (in-place compact).
__global__ __launch_bounds__(256) void ctc_compact(const int* __restrict__ tokens,
                                                   const int* __restrict__ lengths,
                                                   int* __restrict__ out,
                                                   int* __restrict__ out_lengths) {
    const int b = blockIdx.x;
    const int tid = threadIdx.x;
    const int t0 = tid * 8;

    const int* row = tokens + (size_t)b * TDIM;

    // load 8 tokens (2x int4) + predecessor
    int4 lo = ((const int4*)(row + t0))[0];
    int4 hi = ((const int4*)(row + t0))[1];
    int tok[8] = { lo.x, lo.y, lo.z, lo.w, hi.x, hi.y, hi.z, hi.w };
    int prev = (t0 == 0) ? -1 : row[t0 - 1];

    int len = lengths[b];
    if (len < 0) len = 0;
    if (len > TDIM) len = TDIM;

    // thread-local keep flags + exclusive positions
    int pos[8];
    unsigned kb = 0;
    int c = 0;
    #pragma unroll
    for (int j = 0; j < 8; j++) {
        int t = t0 + j;
        int tk = tok[j];
        bool keep = (t < len) & (tk != 0) & (tk != prev);
        pos[j] = c;
        if (keep) { kb |= (1u << j); c++; }
        prev = tk;
    }

    // block exclusive scan of c: wave shuffle scan + 4-wave LDS combine
    int lane = tid & 63;
    int wid = tid >> 6;
    int incl = c;
    #pragma unroll
    for (int off = 1; off < 64; off <<= 1) {
        int n = __shfl_up(incl, off, 64);
        if (lane >= off) incl += n;
    }
    __shared__ int wsum[4];
    if (lane == 63) wsum[wid] = incl;
    __syncthreads();
    int wbase = 0;
    #pragma unroll
    for (int w = 0; w < 4; w++) {
        int s = wsum[w];
        if (w < wid) wbase += s;
    }
    int excl = wbase + incl - c;
    int total = wsum[0] + wsum[1] + wsum[2] + wsum[3];

    // scatter kept tokens to [0, total)
    int* orow = out + (size_t)b * TDIM;
    #pragma unroll
    for (int j = 0; j < 8; j++) {
        if ((kb >> j) & 1u) orow[excl + pos[j]] = tok[j];
    }
    // zero-fill [total, T)  (d_out is poisoned before every run)
    for (int t = total + tid; t < TDIM; t += 256) orow[t] = 0;

    if (tid == 0) out_lengths[b] = total;
}

extern "C" void kernel_launch(void* const* d_in, const int* in_sizes, int n_in,
                              void* d_out, int out_size, void* d_ws, size_t ws_size,
                              hipStream_t stream) {
    (void)d_ws; (void)ws_size; (void)n_in; (void)out_size;
    const float* probs = (const float*)d_in[0];
    const int* lengths = (const int*)d_in[1];
    int* out = (int*)d_out;

    const int B = in_sizes[1];              // 64
    const int nrows = in_sizes[0] / VDIM;   // B*T = 131072

    // tokens scratch aliases d_out (in-place): argmax fills out[0..B*T) with
    // per-(b,t) argmax tokens, ctc_compact then compacts each row in place.
    int* tokens = out;

    // 4 waves/block -> 4 rows/block
    argmax_rows<<<(nrows + 3) / 4, 256, 0, stream>>>(probs, tokens, nrows);
    ctc_compact<<<B, 256, 0, stream>>>(tokens, lengths, out, out + nrows);
}

// Round 3
// 330.585 us; speedup vs baseline: 1.0562x; 1.0536x over previous
//
#include <hip/hip_runtime.h>

// CTC greedy decoder: argmax over V, then per-row unique_consecutive + blank-drop + compact.
// B=64, T=2048, V=512 (fp32 probs, int32 lengths, int32 outputs).
//
// R3 (= R2 with compile fix): attack argmax_rows (~175 us inferred vs 41 us read-roofline).
//  - Nontemporal probs loads: the harness's 1-GiB ws poison fill runs immediately
//    before us each iteration and leaves the 256-MiB LLC fully dirty; cached reads
//    force dirty evictions (writeback traffic against our read stream). NT reads
//    skip LLC allocation. probs has no cross-iteration reuse anyway (fill flushes).
//    (__builtin_nontemporal_load needs a native vector type, not HIP's float4
//    struct -> use ext_vector_type(4).)
//  - 4 rows/wave, 16-lane groups: 8 KB + 8 independent loads in flight per wave,
//    butterfly is 4 width-16 shuffle rounds amortized over 4 rows, 4x fewer
//    waves, coalesced 4-dword token store per wave.

#define VDIM 512
#define TDIM 2048

typedef float  vfloat4 __attribute__((ext_vector_type(4)));

// Block = 256 threads = 4 waves; each wave handles 4 rows (16 lanes/row).
// Lane (g,s): g = row-within-wave, s = 16-lane sublane. Lane s of a row reads
// elements j*64 + s*4 + {0..3} for j = 0..7 (ascending index order -> strict >
// comparisons keep the first occurrence, matching jnp.argmax).
__global__ __launch_bounds__(256) void argmax_rows(const float* __restrict__ probs,
                                                   int* __restrict__ tokens,
                                                   int nrows) {
    const int tid = threadIdx.x;
    const int w = tid >> 6;          // wave id within block
    const int l = tid & 63;
    const int g = l >> 4;            // row group within wave (0..3)
    const int s = l & 15;            // sublane within row (0..15)
    const int row = blockIdx.x * 16 + w * 4 + g;
    if (row >= nrows) return;

    const vfloat4* p = (const vfloat4*)(probs + (size_t)row * VDIM);

    // 8 independent nontemporal 16B loads (memory-level parallelism).
    vfloat4 v[8];
    #pragma unroll
    for (int j = 0; j < 8; j++) {
        v[j] = __builtin_nontemporal_load(&p[j * 16 + s]);
    }

    // Local argmax over 32 elements in ascending-index order (strict > keeps first).
    float bv = v[0].x;
    int bi = s * 4;
    #pragma unroll
    for (int j = 0; j < 8; j++) {
        const int base = j * 64 + s * 4;
        const vfloat4 a = v[j];
        if (j > 0) { if (a.x > bv) { bv = a.x; bi = base; } }
        if (a.y > bv) { bv = a.y; bi = base + 1; }
        if (a.z > bv) { bv = a.z; bi = base + 2; }
        if (a.w > bv) { bv = a.w; bi = base + 3; }
    }

    // Butterfly across the 16-lane group; ties -> lower index (first occurrence).
    #pragma unroll
    for (int off = 8; off > 0; off >>= 1) {
        float ov = __shfl_xor(bv, off, 16);
        int   oi = __shfl_xor(bi, off, 16);
        if (ov > bv || (ov == bv && oi < bi)) { bv = ov; bi = oi; }
    }

    // Lanes s==0 of the 4 groups write 4 consecutive dwords (coalesced).
    if (s == 0) tokens[row] = bi;
}

// One block (256 threads) per batch row; 8 tokens/thread over T=2048.
// keep = (t < len) && (tok != 0) && (tok != prev); prefix-scan; compact left; zero tail.
// All global READS happen before the first __syncthreads (which drains vmcnt on
// gfx950), so the kernel is safe when `tokens` aliases `out` (in-place compact).
__global__ __launch_bounds__(256) void ctc_compact(const int* __restrict__ tokens,
                                                   const int* __restrict__ lengths,
                                                   int* __restrict__ out,
                                                   int* __restrict__ out_lengths) {
    const int b = blockIdx.x;
    const int tid = threadIdx.x;
    const int t0 = tid * 8;

    const int* row = tokens + (size_t)b * TDIM;

    // load 8 tokens (2x int4) + predecessor
    int4 lo = ((const int4*)(row + t0))[0];
    int4 hi = ((const int4*)(row + t0))[1];
    int tok[8] = { lo.x, lo.y, lo.z, lo.w, hi.x, hi.y, hi.z, hi.w };
    int prev = (t0 == 0) ? -1 : row[t0 - 1];

    int len = lengths[b];
    if (len < 0) len = 0;
    if (len > TDIM) len = TDIM;

    // thread-local keep flags + exclusive positions
    int pos[8];
    unsigned kb = 0;
    int c = 0;
    #pragma unroll
    for (int j = 0; j < 8; j++) {
        int t = t0 + j;
        int tk = tok[j];
        bool keep = (t < len) & (tk != 0) & (tk != prev);
        pos[j] = c;
        if (keep) { kb |= (1u << j); c++; }
        prev = tk;
    }

    // block exclusive scan of c: wave shuffle scan + 4-wave LDS combine
    int lane = tid & 63;
    int wid = tid >> 6;
    int incl = c;
    #pragma unroll
    for (int off = 1; off < 64; off <<= 1) {
        int n = __shfl_up(incl, off, 64);
        if (lane >= off) incl += n;
    }
    __shared__ int wsum[4];
    if (lane == 63) wsum[wid] = incl;
    __syncthreads();
    int wbase = 0;
    #pragma unroll
    for (int w = 0; w < 4; w++) {
        int s = wsum[w];
        if (w < wid) wbase += s;
    }
    int excl = wbase + incl - c;
    int total = wsum[0] + wsum[1] + wsum[2] + wsum[3];

    // scatter kept tokens to [0, total)
    int* orow = out + (size_t)b * TDIM;
    #pragma unroll
    for (int j = 0; j < 8; j++) {
        if ((kb >> j) & 1u) orow[excl + pos[j]] = tok[j];
    }
    // zero-fill [total, T)  (d_out is poisoned before every run)
    for (int t = total + tid; t < TDIM; t += 256) orow[t] = 0;

    if (tid == 0) out_lengths[b] = total;
}

extern "C" void kernel_launch(void* const* d_in, const int* in_sizes, int n_in,
                              void* d_out, int out_size, void* d_ws, size_t ws_size,
                              hipStream_t stream) {
    (void)d_ws; (void)ws_size; (void)n_in; (void)out_size;
    const float* probs = (const float*)d_in[0];
    const int* lengths = (const int*)d_in[1];
    int* out = (int*)d_out;

    const int B = in_sizes[1];              // 64
    const int nrows = in_sizes[0] / VDIM;   // B*T = 131072

    // tokens scratch aliases d_out (in-place): argmax fills out[0..B*T) with
    // per-(b,t) argmax tokens, ctc_compact then compacts each row in place.
    int* tokens = out;

    // 16 rows per 256-thread block (4 waves x 4 rows/wave)
    argmax_rows<<<(nrows + 15) / 16, 256, 0, stream>>>(probs, tokens, nrows);
    ctc_compact<<<B, 256, 0, stream>>>(tokens, lengths, out, out + nrows);
}